// Round 2
// baseline (1994.800 us; speedup 1.0000x reference)
//
#include <hip/hip_runtime.h>
#include <hip/hip_bf16.h>
#include <math.h>

#define T_TOK 4096
#define H_DIM 2048
#define D_DIM 2048
#define TWO_D 4096
#define E_NUM 16
#define NPAIR (T_TOK * 4)

typedef __attribute__((ext_vector_type(8))) short v8s;
typedef __attribute__((ext_vector_type(4))) float v4f;

__device__ __forceinline__ ushort f2bf(float f) {
    union { float f; unsigned u; } v; v.f = f;
    unsigned u = v.u + 0x7fffu + ((v.u >> 16) & 1u);
    return (ushort)(u >> 16);
}
__device__ __forceinline__ float bf2f(ushort b) {
    union { unsigned u; float f; } v; v.u = ((unsigned)b) << 16;
    return v.f;
}

// async global->LDS, 16B per lane; LDS dest is wave-uniform base + lane*16
__device__ __forceinline__ void async16(ushort* lds, const ushort* g) {
    __builtin_amdgcn_global_load_lds(
        (const __attribute__((address_space(1))) unsigned int*)g,
        (__attribute__((address_space(3))) unsigned int*)lds, 16, 0, 0);
}

// ---------------- convert x to bf16 ----------------
__global__ void k_convert_x(const float* __restrict__ x, ushort* __restrict__ xb) {
    size_t i = ((size_t)blockIdx.x * 256 + threadIdx.x) * 4;
    float4 v = *(const float4*)(x + i);
    *(ushort4*)(xb + i) = make_ushort4(f2bf(v.x), f2bf(v.y), f2bf(v.z), f2bf(v.w));
}

// ---------------- weight convert + transpose: fp32 [e][K][N] -> bf16 [e][N][K] ----------------
__global__ __launch_bounds__(256) void k_transpose(const float* __restrict__ W,
                                                   ushort* __restrict__ Wt,
                                                   int K, int N) {
    __shared__ ushort tile[64][72];  // [n][k], pad to 72 ushorts
    const int e = blockIdx.z;
    const int kb = blockIdx.y * 64;
    const int nb = blockIdx.x * 64;
    const int tid = threadIdx.x;
    const float* src = W + ((size_t)e * K + kb) * N + nb;
    #pragma unroll
    for (int i = 0; i < 4; i++) {
        int lin = tid + 256 * i;
        int r = lin >> 4, c4 = (lin & 15) * 4;       // r = k-row, c4 = n-col
        float4 v = *(const float4*)(src + (size_t)r * N + c4);
        tile[c4 + 0][r] = f2bf(v.x);
        tile[c4 + 1][r] = f2bf(v.y);
        tile[c4 + 2][r] = f2bf(v.z);
        tile[c4 + 3][r] = f2bf(v.w);
    }
    __syncthreads();
    ushort* dst = Wt + ((size_t)e * N + nb) * K + kb;
    #pragma unroll
    for (int j = 0; j < 2; j++) {
        int lin = tid + 256 * j;
        int n = lin >> 3, kc = (lin & 7) * 8;
        ushort4 a = *(const ushort4*)&tile[n][kc];
        ushort4 b = *(const ushort4*)&tile[n][kc + 4];
        *(ushort4*)(dst + (size_t)n * K + kc) = a;
        *(ushort4*)(dst + (size_t)n * K + kc + 4) = b;
    }
}

// ---------------- router logits (fp32) ----------------
__global__ void k_router(const float* __restrict__ x, const float* __restrict__ rw,
                         const float* __restrict__ rb, float* __restrict__ logits) {
    int t = blockIdx.x;
    int e = threadIdx.x >> 4;
    int j = threadIdx.x & 15;
    const float4* xr = (const float4*)(x + (size_t)t * H_DIM);
    const float4* wr = (const float4*)(rw + (size_t)e * H_DIM);
    float s = 0.f;
    #pragma unroll 8
    for (int h = j; h < H_DIM / 4; h += 16) {
        float4 a = xr[h], b = wr[h];
        s += a.x * b.x + a.y * b.y + a.z * b.z + a.w * b.w;
    }
    #pragma unroll
    for (int d = 8; d >= 1; d >>= 1) s += __shfl_down(s, d, 16);
    if (j == 0) logits[t * E_NUM + e] = s + rb[e];
}

// ---------------- top-k + softmax ----------------
__global__ void k_topk(const float* __restrict__ logits, float* __restrict__ scores_out,
                       int* __restrict__ tk_e, float* __restrict__ tk_w,
                       int* __restrict__ counts) {
    int t = blockIdx.x * 256 + threadIdx.x;
    if (t >= T_TOK) return;
    float lg[E_NUM];
    #pragma unroll
    for (int e = 0; e < E_NUM; e++) lg[e] = logits[t * E_NUM + e];
    int sel[4]; float sv[4];
    unsigned used = 0;
    #pragma unroll
    for (int k = 0; k < 4; k++) {
        float best = -INFINITY; int bi = 0;
        #pragma unroll
        for (int e = 0; e < E_NUM; e++) {
            if (!((used >> e) & 1) && lg[e] > best) { best = lg[e]; bi = e; }
        }
        used |= 1u << bi; sel[k] = bi; sv[k] = best;
    }
    float m = sv[0];
    float ex[4]; float sum = 0.f;
    #pragma unroll
    for (int k = 0; k < 4; k++) { ex[k] = __expf(sv[k] - m); sum += ex[k]; }
    float inv = 1.f / sum;
    #pragma unroll
    for (int k = 0; k < 4; k++) {
        float w = ex[k] * inv;
        scores_out[t * 4 + k] = w * 0.25f;
        tk_e[t * 4 + k] = sel[k];
        tk_w[t * 4 + k] = w;
        atomicAdd(&counts[sel[k]], 1);
    }
}

// ---------------- scan counts -> offsets ----------------
__global__ void k_scan(const int* __restrict__ counts, int* __restrict__ offsets) {
    if (threadIdx.x == 0) {
        int s = 0;
        for (int e = 0; e < E_NUM; e++) { offsets[e] = s; s += counts[e]; }
        offsets[E_NUM] = s;
    }
}

// ---------------- scatter pairs into expert-grouped order ----------------
__global__ void k_scatter(const int* __restrict__ tk_e, const int* __restrict__ offsets,
                          int* __restrict__ fill, int* __restrict__ pair_token,
                          int* __restrict__ slot_of) {
    int i = blockIdx.x * 256 + threadIdx.x;
    if (i >= NPAIR) return;
    int e = tk_e[i];
    int pos = offsets[e] + atomicAdd(&fill[e], 1);
    pair_token[pos] = i >> 2;
    slot_of[i] = pos;
}

// ---------------- unified GEMM: out[m][n] = A[m] . Bt[n] + bias[n], bf16 MFMA ----------------
// A: bf16 [rows][K] (GATHER: row index via pair_token; else row = off+m)
// Bt: bf16 [e][N][K] (pre-transposed weights)
// LDS: fragment-major — subtile(xblk,ks) = 64 lanes x 16B contiguous, ds_read_b128 at lane*16
#define BM 128
#define BN 128
#define BK 64

template <bool GATHER>
__global__ __launch_bounds__(256) void k_gemm(
    const ushort* __restrict__ A, const ushort* __restrict__ Bt,
    const float* __restrict__ bias, const int* __restrict__ offsets,
    const int* __restrict__ pair_token, ushort* __restrict__ out,
    int N, int K)
{
    __shared__ ushort As[BM * BK];  // 16 subtiles x 512 ushorts
    __shared__ ushort Bs[BN * BK];

    const int e = blockIdx.z;
    const int off = offsets[e];
    const int cnt = offsets[e + 1] - off;
    const int m0 = blockIdx.y * BM;
    if (m0 >= cnt) return;
    const int n0 = blockIdx.x * BN;
    const int tid = threadIdx.x;
    const int wave = tid >> 6;
    const int lane = tid & 63;
    const int lm = lane & 15;
    const int kg = lane >> 4;

    // staging source rows for this wave: A mblk = 2w, 2w+1; B nblk = 2w, 2w+1
    int ar0 = m0 + (2 * wave) * 16 + lm;       if (ar0 >= cnt) ar0 = cnt - 1;
    int ar1 = m0 + (2 * wave + 1) * 16 + lm;   if (ar1 >= cnt) ar1 = cnt - 1;
    const ushort* aptr0 = A + (size_t)(GATHER ? pair_token[off + ar0] : off + ar0) * K + kg * 8;
    const ushort* aptr1 = A + (size_t)(GATHER ? pair_token[off + ar1] : off + ar1) * K + kg * 8;
    const ushort* bbase = Bt + (size_t)e * N * K;
    const ushort* bptr0 = bbase + (size_t)(n0 + (2 * wave) * 16 + lm) * K + kg * 8;
    const ushort* bptr1 = bbase + (size_t)(n0 + (2 * wave + 1) * 16 + lm) * K + kg * 8;

    ushort* asub = &As[(4 * wave) * 512];
    ushort* bsub = &Bs[(4 * wave) * 512];

    v4f acc[4][4];
    #pragma unroll
    for (int i = 0; i < 4; i++)
        #pragma unroll
        for (int j = 0; j < 4; j++) acc[i][j] = (v4f){0.f, 0.f, 0.f, 0.f};

    const int mb = (wave & 1) * 4;   // mblk base for compute
    const int nb = (wave >> 1) * 4;  // nblk base for compute

    for (int kb = 0; kb < K; kb += BK) {
        __syncthreads();
        async16(asub,        aptr0 + kb);
        async16(asub + 512,  aptr0 + kb + 32);
        async16(asub + 1024, aptr1 + kb);
        async16(asub + 1536, aptr1 + kb + 32);
        async16(bsub,        bptr0 + kb);
        async16(bsub + 512,  bptr0 + kb + 32);
        async16(bsub + 1024, bptr1 + kb);
        async16(bsub + 1536, bptr1 + kb + 32);
        __syncthreads();
        #pragma unroll
        for (int ks = 0; ks < 2; ks++) {
            v8s af[4], bfr[4];
            #pragma unroll
            for (int mi = 0; mi < 4; mi++)
                af[mi] = *(const v8s*)&As[((mb + mi) * 2 + ks) * 512 + lane * 8];
            #pragma unroll
            for (int ni = 0; ni < 4; ni++)
                bfr[ni] = *(const v8s*)&Bs[((nb + ni) * 2 + ks) * 512 + lane * 8];
            #pragma unroll
            for (int mi = 0; mi < 4; mi++)
                #pragma unroll
                for (int ni = 0; ni < 4; ni++)
                    acc[mi][ni] = __builtin_amdgcn_mfma_f32_16x16x32_bf16(af[mi], bfr[ni], acc[mi][ni], 0, 0, 0);
        }
    }

    const int wm = (wave & 1) * 64;
    const int wn = (wave >> 1) * 64;
    const float* bp = bias + (size_t)e * N + n0;
    #pragma unroll
    for (int mi = 0; mi < 4; mi++) {
        int rbase = wm + mi * 16 + kg * 4;
        #pragma unroll
        for (int ni = 0; ni < 4; ni++) {
            int nl = wn + ni * 16 + lm;
            float bv = bp[nl];
            #pragma unroll
            for (int v = 0; v < 4; v++) {
                int r = rbase + v;
                if (m0 + r < cnt)
                    out[(size_t)(off + m0 + r) * N + n0 + nl] = f2bf(acc[mi][ni][v] + bv);
            }
        }
    }
}

// ---------------- activation: clamp + GLU -> gated (bf16) ----------------
__global__ void k_act(const ushort* __restrict__ gu, ushort* __restrict__ gated) {
    int i = blockIdx.x * 256 + threadIdx.x;
    int pr = i >> 9;
    int q = (i & 511) * 4;
    const ushort* grow = gu + (size_t)pr * TWO_D;
    ushort4 g4 = *(const ushort4*)(grow + q);
    ushort4 u4 = *(const ushort4*)(grow + D_DIM + q);
    float g[4] = { bf2f(g4.x), bf2f(g4.y), bf2f(g4.z), bf2f(g4.w) };
    float u[4] = { bf2f(u4.x), bf2f(u4.y), bf2f(u4.z), bf2f(u4.w) };
    ushort o[4];
    #pragma unroll
    for (int j = 0; j < 4; j++) {
        float gate = fminf(g[j], 7.f);
        float up = fminf(fmaxf(u[j], -7.f), 7.f);
        float glu = gate / (1.f + __expf(-1.702f * gate));
        o[j] = f2bf((up + 1.f) * glu);
    }
    *(ushort4*)(gated + (size_t)pr * D_DIM + q) = make_ushort4(o[0], o[1], o[2], o[3]);
}

// ---------------- combine ----------------
__global__ void k_combine(const ushort* __restrict__ po, const int* __restrict__ slot_of,
                          const float* __restrict__ tk_w, float* __restrict__ y) {
    const int t = blockIdx.x;
    int s[4]; float w[4];
    #pragma unroll
    for (int k = 0; k < 4; k++) { s[k] = slot_of[t * 4 + k]; w[k] = tk_w[t * 4 + k]; }
    const int h = threadIdx.x * 8;
    float acc[8];
    #pragma unroll
    for (int j = 0; j < 8; j++) acc[j] = 0.f;
    #pragma unroll
    for (int k = 0; k < 4; k++) {
        const ushort* row = po + (size_t)s[k] * H_DIM + h;
        ushort4 a = *(const ushort4*)row;
        ushort4 b = *(const ushort4*)(row + 4);
        acc[0] += w[k] * bf2f(a.x); acc[1] += w[k] * bf2f(a.y);
        acc[2] += w[k] * bf2f(a.z); acc[3] += w[k] * bf2f(a.w);
        acc[4] += w[k] * bf2f(b.x); acc[5] += w[k] * bf2f(b.y);
        acc[6] += w[k] * bf2f(b.z); acc[7] += w[k] * bf2f(b.w);
    }
    float* yp = y + (size_t)t * H_DIM + h;
    *(float4*)yp = make_float4(acc[0], acc[1], acc[2], acc[3]);
    *(float4*)(yp + 4) = make_float4(acc[4], acc[5], acc[6], acc[7]);
}

extern "C" void kernel_launch(void* const* d_in, const int* in_sizes, int n_in,
                              void* d_out, int out_size, void* d_ws, size_t ws_size,
                              hipStream_t stream) {
    const float* x   = (const float*)d_in[0];
    const float* rw  = (const float*)d_in[1];
    const float* rb  = (const float*)d_in[2];
    const float* wgu = (const float*)d_in[3];
    const float* bgu = (const float*)d_in[4];
    const float* wd  = (const float*)d_in[5];
    const float* bd  = (const float*)d_in[6];
    float* y = (float*)d_out;
    float* scores = y + (size_t)T_TOK * H_DIM;

    char* p = (char*)d_ws;
    auto alloc = [&](size_t bytes) { char* r = p; p += (bytes + 255) & ~(size_t)255; return r; };
    ushort* xb         = (ushort*)alloc((size_t)T_TOK * H_DIM * 2);          // 16 MB
    ushort* wgu_t      = (ushort*)alloc((size_t)E_NUM * TWO_D * H_DIM * 2);  // 256 MB
    ushort* wd_t       = (ushort*)alloc((size_t)E_NUM * H_DIM * D_DIM * 2);  // 128 MB
    float*  logits     = (float*) alloc((size_t)T_TOK * E_NUM * 4);
    int*    tk_e       = (int*)   alloc(NPAIR * 4);
    float*  tk_w       = (float*) alloc(NPAIR * 4);
    int*    slot_of    = (int*)   alloc(NPAIR * 4);
    int*    pair_token = (int*)   alloc(NPAIR * 4);
    int*    cnt_fill   = (int*)   alloc(512);
    int*    offsets    = (int*)   alloc(128);
    ushort* gu         = (ushort*)alloc((size_t)NPAIR * TWO_D * 2);          // 128 MB
    ushort* gated      = (ushort*)alloc((size_t)NPAIR * D_DIM * 2);          // 64 MB
    ushort* pairout    = gu;  // alias: gu dead after k_act
    int* counts = cnt_fill;
    int* fill   = cnt_fill + 64;

    hipMemsetAsync(cnt_fill, 0, 512, stream);
    k_convert_x<<<(T_TOK * H_DIM) / (256 * 4), 256, 0, stream>>>(x, xb);
    k_transpose<<<dim3(TWO_D / 64, H_DIM / 64, E_NUM), 256, 0, stream>>>(wgu, wgu_t, H_DIM, TWO_D);
    k_transpose<<<dim3(H_DIM / 64, D_DIM / 64, E_NUM), 256, 0, stream>>>(wd, wd_t, D_DIM, H_DIM);
    k_router<<<T_TOK, 256, 0, stream>>>(x, rw, rb, logits);
    k_topk<<<T_TOK / 256, 256, 0, stream>>>(logits, scores, tk_e, tk_w, counts);
    k_scan<<<1, 64, 0, stream>>>(counts, offsets);
    k_scatter<<<NPAIR / 256, 256, 0, stream>>>(tk_e, offsets, fill, pair_token, slot_of);
    k_gemm<true><<<dim3(TWO_D / BN, T_TOK / BM, E_NUM), 256, 0, stream>>>(
        xb, wgu_t, bgu, offsets, pair_token, gu, TWO_D, H_DIM);
    k_act<<<(NPAIR * 512) / 256, 256, 0, stream>>>(gu, gated);
    k_gemm<false><<<dim3(H_DIM / BN, T_TOK / BM, E_NUM), 256, 0, stream>>>(
        gated, wd_t, bd, offsets, pair_token, pairout, H_DIM, D_DIM);
    k_combine<<<T_TOK, 256, 0, stream>>>(pairout, slot_of, tk_w, y);
}